// Round 11
// baseline (595.159 us; speedup 1.0000x reference)
//
#include <hip/hip_runtime.h>
#include <hip/hip_cooperative_groups.h>
#include <hip/hip_bf16.h>

namespace cg = cooperative_groups;

// RUDY routing-demand maps via difference-domain + 2D prefix sum, fully
// fused into ONE cooperative kernel.
//
// Round-11 rationale: r10 showed the 7-kernel pipeline's work is only
// ~25-35 us; the remaining ~45 us is per-dispatch overhead + graph-node
// gaps (~5-6 us/node, measured via r9->r10 node-count delta). Fix: single
// hipLaunchCooperativeKernel with 5 grid.sync()s. Phases:
//  P1 bbox (1 thread/net) + per-block pair histogram -> ghist (non-atomic)
//  P2 per-pair exclusive prefix over blocks (128 blocks) -> rel, gcount
//  P4 placement at deterministic offsets (LDS cursors; zero global atomics)
//  P5 balanced chunk build (<=1024 items/chunk; plan recomputed in LDS)
//  P6 fold chunks + inclusive y-scan -> D
//  P7 inclusive x-scan + finalize -> out
// No memsets needed: every word read was written this launch.

#define NBX 256
#define NBY 256
#define NMAP (NBX * NBY)
#define NPAIR 128
#define GRID 1024
#define ITEMS 1024u

constexpr float BSX = 2.0f;
constexpr float BSY = 2.0f;
constexpr float INV_H = 1.0f / (4.0f * 50.0f);
constexpr float INV_V = 1.0f / (4.0f * 40.0f);

__device__ __forceinline__ float seg_cum(float t, float mn, float mx) {
    return fminf(fmaxf(t, mn), mx) - mn;
}
// First difference of per-bin overlap of [mn,mx]; nonzero only at
// {i0, i0+1, i1, i1+1}.
__device__ __forceinline__ float second_diff(int i, float bs, float mn, float mx) {
    float u2 = seg_cum((float)(i + 1) * bs, mn, mx);
    float u1 = seg_cum((float)(i) * bs, mn, mx);
    float u0 = seg_cum((float)(i - 1) * bs, mn, mx);
    return (u2 - u1) - (u1 - u0);
}
// Row-pair buckets this net touches (deduped, <=4).
__device__ __forceinline__ int net_pairs(float4 bb, int* pl) {
    if (bb.y < bb.x) return 0;                 // sentinel / degenerate
    int i0 = (int)floorf(bb.x * 0.5f);
    int i1 = (int)floorf(bb.y * 0.5f);
    int a = i0 >> 1, b = (i0 + 1) >> 1, c = i1 >> 1, d = (i1 + 1) >> 1;
    int n = 0;
    pl[n++] = a;
    if (b != a && b < NPAIR) pl[n++] = b;
    if (c != a && c != b) pl[n++] = c;
    if (d != a && d != b && d != c && d < NPAIR) pl[n++] = d;
    return n;
}

__global__ void __launch_bounds__(256, 4) rudy_fused(
    const float* __restrict__ pin_pos,
    const int* __restrict__ netpin_start,
    const int* __restrict__ flat_netpin,
    const float* __restrict__ net_weights,
    const float* __restrict__ init_h,
    const float* __restrict__ init_v,
    float4* __restrict__ bbox4,
    unsigned* __restrict__ ghist,    // [GRID][NPAIR]
    unsigned* __restrict__ gcount,   // [NPAIR]
    int* __restrict__ bucket,
    float2* __restrict__ Dsub,       // [C][2][NBY]
    float2* __restrict__ D,          // [NBX][NBY]
    float* __restrict__ out,
    int num_nets) {
    cg::grid_group grid = cg::this_grid();
    const int tid = threadIdx.x;
    const int bid = blockIdx.x;

    __shared__ unsigned u0[NPAIR], u1[NPAIR], u2[NPAIR];
    __shared__ unsigned scan256[256];
    __shared__ float rA[256], rB[256], rC[256], rD[256];
    __shared__ int ch_pair, ch_beg, ch_end;

    // ---------- P1: bbox + per-block pair histogram ----------
    if (tid < NPAIR) u0[tid] = 0u;
    __syncthreads();
    for (int n = bid * 256 + tid; n < num_nets; n += GRID * 256) {
        int s = netpin_start[n], e = netpin_start[n + 1];
        float xmn = 3.0e38f, xmx = -3.0e38f, ymn = 3.0e38f, ymx = -3.0e38f;
        for (int p = s; p < e; ++p) {
            int ip = flat_netpin[p];
            float2 xy = *reinterpret_cast<const float2*>(pin_pos + 2 * (size_t)ip);
            xmn = fminf(xmn, xy.x);
            xmx = fmaxf(xmx, xy.x);
            ymn = fminf(ymn, xy.y);
            ymx = fmaxf(ymx, xy.y);
        }
        float4 bb = (e <= s) ? make_float4(3.0e38f, -3.0e38f, 3.0e38f, -3.0e38f)
                             : make_float4(xmn, xmx, ymn, ymx);
        bbox4[n] = bb;
        int pl[4];
        int k = net_pairs(bb, pl);
        for (int i = 0; i < k; ++i) atomicAdd(&u0[pl[i]], 1u);
    }
    __syncthreads();
    if (tid < NPAIR) ghist[(size_t)bid * NPAIR + tid] = u0[tid];
    grid.sync();

    // ---------- P2: per-pair exclusive prefix over blocks ----------
    if (bid < NPAIR) {
        const int p = bid;
        const int b0 = tid * 4;                 // GRID == 256*4
        unsigned v[4], tpre[4], acc = 0;
#pragma unroll
        for (int j = 0; j < 4; ++j) v[j] = ghist[(size_t)(b0 + j) * NPAIR + p];
#pragma unroll
        for (int j = 0; j < 4; ++j) { tpre[j] = acc; acc += v[j]; }
        scan256[tid] = acc;
        __syncthreads();
        for (int off = 1; off < 256; off <<= 1) {
            unsigned a = (tid >= off) ? scan256[tid - off] : 0u;
            __syncthreads();
            scan256[tid] += a;
            __syncthreads();
        }
        unsigned excl = scan256[tid] - acc;
#pragma unroll
        for (int j = 0; j < 4; ++j)
            ghist[(size_t)(b0 + j) * NPAIR + p] = excl + tpre[j];   // rel offsets
        if (tid == 255) gcount[p] = scan256[255];
    }
    grid.sync();

    // ---------- P4: placement at deterministic offsets ----------
    if (tid < NPAIR) {
        u0[tid] = gcount[tid];                          // -> inclusive prefix
        u1[tid] = ghist[(size_t)bid * NPAIR + tid];     // rel for this block
        u2[tid] = 0u;                                   // LDS cursor
    }
    __syncthreads();
    for (int off = 1; off < NPAIR; off <<= 1) {
        unsigned a = (tid < NPAIR && tid >= off) ? u0[tid - off] : 0u;
        __syncthreads();
        if (tid < NPAIR) u0[tid] += a;
        __syncthreads();
    }
    for (int n = bid * 256 + tid; n < num_nets; n += GRID * 256) {
        float4 bb = bbox4[n];
        int pl[4];
        int k = net_pairs(bb, pl);
        for (int i = 0; i < k; ++i) {
            int p = pl[i];
            unsigned local = atomicAdd(&u2[p], 1u);
            unsigned base = (p ? u0[p - 1] : 0u) + u1[p];
            bucket[base + local] = n;
        }
    }
    grid.sync();

    // ---------- P5: chunk plan (in LDS) + balanced build ----------
    // u0 still holds the inclusive bucket-base prefix.
    if (tid < NPAIR) {
        unsigned c = gcount[tid];
        u1[tid] = 1u + c / ITEMS;                       // kc per pair
        u2[tid] = u1[tid];                              // -> inclusive prefix
    }
    __syncthreads();
    for (int off = 1; off < NPAIR; off <<= 1) {
        unsigned a = (tid < NPAIR && tid >= off) ? u2[tid - off] : 0u;
        __syncthreads();
        if (tid < NPAIR) u2[tid] += a;
        __syncthreads();
    }
    const int C = (int)u2[NPAIR - 1];
    for (int c = bid; c < C; c += GRID) {
        if (tid < NPAIR) {
            unsigned hi = u2[tid];
            unsigned lo = tid ? u2[tid - 1] : 0u;
            if ((unsigned)c >= lo && (unsigned)c < hi) {
                int p = tid;
                unsigned cnt = gcount[p];
                unsigned obeg = p ? u0[p - 1] : 0u;
                unsigned kc = u1[p];
                unsigned j = (unsigned)c - lo;
                unsigned span = (cnt + kc - 1u) / kc;
                unsigned b = obeg + j * span;
                unsigned e2 = min(b + span, obeg + cnt);
                if (b > e2) b = e2;
                ch_pair = p;
                ch_beg = (int)b;
                ch_end = (int)e2;
            }
        }
        rA[tid] = 0.f; rB[tid] = 0.f; rC[tid] = 0.f; rD[tid] = 0.f;
        __syncthreads();
        const int pair = ch_pair, beg = ch_beg, end = ch_end;
        const int r0 = pair * 2, r1 = r0 + 1;
        for (int q = beg + tid; q < end; q += 256) {
            int id = bucket[q];
            float4 bb = bbox4[id];
            float w = net_weights[id];
            float wh = w / (bb.w - bb.z);
            float wv = w / (bb.y - bb.x);
            float dA = second_diff(r0, BSX, bb.x, bb.y);
            float dB = second_diff(r1, BSX, bb.x, bb.y);
            int j0 = (int)floorf(bb.z * 0.5f);
            int j1 = (int)floorf(bb.w * 0.5f);
            int yi[4];
            yi[0] = j0;
            yi[1] = j0 + 1;
            yi[2] = (j1 > j0 + 1) ? j1 : -1;
            yi[3] = (j1 > j0) ? j1 + 1 : -1;
#pragma unroll
            for (int c2 = 0; c2 < 4; ++c2) {
                int y = yi[c2];
                if (y >= 0 && y < NBY) {
                    float dy = second_diff(y, BSY, bb.z, bb.w);
                    if (dy != 0.0f) {
                        if (dA != 0.0f) {
                            atomicAdd(&rA[y], wh * dA * dy);
                            atomicAdd(&rB[y], wv * dA * dy);
                        }
                        if (dB != 0.0f) {
                            atomicAdd(&rC[y], wh * dB * dy);
                            atomicAdd(&rD[y], wv * dB * dy);
                        }
                    }
                }
            }
        }
        __syncthreads();
        Dsub[(size_t)c * 2 * NBY + tid]       = make_float2(rA[tid], rB[tid]);
        Dsub[(size_t)c * 2 * NBY + NBY + tid] = make_float2(rC[tid], rD[tid]);
        __syncthreads();
    }
    grid.sync();

    // ---------- P6: fold chunks + inclusive y-scan ----------
    // u1 (kc) and u2 (kc inclusive prefix) still valid in LDS.
    if (bid < NBX) {
        const int r = bid, p = r >> 1, par = r & 1;
        unsigned kb = p ? u2[p - 1] : 0u;
        unsigned kc = u1[p];
        float h = 0.f, v = 0.f;
        for (unsigned j = 0; j < kc; ++j) {
            float2 t = Dsub[((size_t)(kb + j) * 2 + par) * NBY + tid];
            h += t.x;
            v += t.y;
        }
        rA[tid] = h;
        rB[tid] = v;
        __syncthreads();
        for (int off = 1; off < NBY; off <<= 1) {
            float ah = (tid >= off) ? rA[tid - off] : 0.f;
            float av = (tid >= off) ? rB[tid - off] : 0.f;
            __syncthreads();
            rA[tid] += ah;
            rB[tid] += av;
            __syncthreads();
        }
        D[r * NBY + tid] = make_float2(rA[tid], rB[tid]);
    }
    grid.sync();

    // ---------- P7: inclusive x-scan + finalize ----------
    if (bid < NBY) {
        const int y = bid;
        float2 t = D[tid * NBY + y];
        rA[tid] = t.x;
        rB[tid] = t.y;
        __syncthreads();
        for (int off = 1; off < NBX; off <<= 1) {
            float ah = (tid >= off) ? rA[tid - off] : 0.f;
            float av = (tid >= off) ? rB[tid - off] : 0.f;
            __syncthreads();
            rA[tid] += ah;
            rB[tid] += av;
            __syncthreads();
        }
        int idx = tid * NBY + y;
        float H = fmaf(rA[tid], INV_H, init_h[idx]);
        float V = fmaf(rB[tid], INV_V, init_v[idx]);
        float rr = fmaxf(fabsf(H), fabsf(V));
        out[idx]            = rr;
        out[idx + NMAP]     = H;
        out[idx + 2 * NMAP] = V;
    }
}

extern "C" void kernel_launch(void* const* d_in, const int* in_sizes, int n_in,
                              void* d_out, int out_size, void* d_ws, size_t ws_size,
                              hipStream_t stream) {
    const float* pin_pos      = (const float*)d_in[0];
    const int*   netpin_start = (const int*)d_in[1];
    const int*   flat_netpin  = (const int*)d_in[2];
    const float* net_weights  = (const float*)d_in[3];
    const float* init_h       = (const float*)d_in[4];
    const float* init_v       = (const float*)d_in[5];
    float* out = (float*)d_out;

    int num_nets = in_sizes[3];
    int Np = (num_nets + 255) & ~255;
    int maxch = NPAIR + (4 * Np) / (int)ITEMS + 1;

    // ws layout (~6.3 MB @100k nets), every region written before read:
    // [bbox4 Np*16][ghist GRID*128*4][gcount 512][bucket 4*Np*4]
    // [Dsub maxch*2*256*8][D NMAP*8]
    char* w = (char*)d_ws;
    size_t o = 0;
    float4*   bbox4  = (float4*)(w + o);   o += (size_t)Np * 16;
    unsigned* ghist  = (unsigned*)(w + o); o += (size_t)GRID * NPAIR * 4;
    unsigned* gcount = (unsigned*)(w + o); o += 512;
    int*      bucket = (int*)(w + o);      o += (size_t)4 * Np * 4;
    float2*   Dsub   = (float2*)(w + o);   o += (size_t)maxch * 2 * NBY * 8;
    float2*   D      = (float2*)(w + o);   o += (size_t)NMAP * 8;

    void* args[] = {(void*)&pin_pos, (void*)&netpin_start, (void*)&flat_netpin,
                    (void*)&net_weights, (void*)&init_h, (void*)&init_v,
                    (void*)&bbox4, (void*)&ghist, (void*)&gcount, (void*)&bucket,
                    (void*)&Dsub, (void*)&D, (void*)&out, (void*)&num_nets};
    hipLaunchCooperativeKernel((const void*)rudy_fused, dim3(GRID), dim3(256),
                               args, 0, stream);
}